// Round 13
// baseline (251.322 us; speedup 1.0000x reference)
//
#include <hip/hip_runtime.h>

// B=4 T=4096 D=1024 H=16 HD=64 K=32 ; inputs f32, OUTPUTS f32.
// NO d_ws usage: all scratch lives inside the 67.1 MB f32 output-0 region.
// Zero atomics. r11 revision: thinner partial slabs (k1 z=32, qkv z=8),
// single-stage reduces (9 dispatches total, was 11).
#define B_ 4
#define T_ 4096
#define D_ 1024
#define H_ 16
#define K_ 32

// ---------------------------------------------------------------------------
// Scratch layout (f32 indices into outF; out0 = floats [0, 16777216)):
//   xs    [0      ,131072)   B*K x 1024   [reduce_zp dst]
//   xbar  [131072 ,135168)   B x 1024     [reduce_zp dst, contiguous w/ xs]
//   pad   [135168 ,196608)   zeros (rows 132..191 of gemm#1 A) [reduce_zp]
//   qkv   [196608 ,786432)   192 x 3072   [reduce_z dst]
//   u     [786432 ,917504)   128 x 1024   [pure write, k3]
//   Mm    [917504 ,1048576)  128 x 1024   [reduce_z dst] = out0 rows [896,1024)
//   S     [1048576,...) partial slabs, sequentially reused (in-order stream):
//     k1 partials  : 32 z-records of 135168 = [1048576, 5374976)
//     qkv partials : 8 x 589824             = [1048576, 5767168)
//     gemm2 partials: 16 x 131072           = [1048576, 3145728)
//   pulse outF[16777216 +64), resp outF[16777280 +2048)
// Lessons: (r7/r8) dependent rotating prefetch serializes on latency -> use
// memcpy-shaped burst staging; manual 1-deep prefetch (issue next stage's
// bursts BEFORE current compute). (r8) fat register caches kill occupancy ->
// stream L2-hot data, hold only accumulators. (r4) LDS cost ~ bytes
// delivered to RF -> keep FMA:LDS-byte ratio high. (r11) partial-slab
// round-trips cost ~13us -> halve z-splits, single-stage reduces.
// ---------------------------------------------------------------------------

__device__ __forceinline__ void fma4(float4& a, float s, const float4& v){
  a.x = fmaf(s, v.x, a.x); a.y = fmaf(s, v.y, a.y);
  a.z = fmaf(s, v.z, a.z); a.w = fmaf(s, v.w, a.w);
}

// reduce_zp: dst[i] = sum_z src[z*stride4+i] for i<n4; dst[i]=0 for
// n4<=i<total4 (zeroes gemm#1's pad rows).
__global__ __launch_bounds__(256) void reduce_zp(
    const float4* __restrict__ src, float4* __restrict__ dst,
    const int n4, const int z, const int stride4, const int total4)
{
  int i = blockIdx.x * 256 + threadIdx.x;
  if (i >= total4) return;
  if (i >= n4){
    float4 zv; zv.x = 0.f; zv.y = 0.f; zv.z = 0.f; zv.w = 0.f;
    dst[i] = zv; return;
  }
  float s0 = 0.f, s1 = 0.f, s2 = 0.f, s3 = 0.f;
  const float4* p = src + i;
  #pragma unroll 8
  for (int zz = 0; zz < z; ++zz){
    float4 v = p[(size_t)zz * stride4];
    s0 += v.x; s1 += v.y; s2 += v.z; s3 += v.w;
  }
  float4 o; o.x = s0; o.y = s1; o.z = s2; o.w = s3;
  dst[i] = o;
}

__global__ __launch_bounds__(256) void reduce_z(
    const float4* __restrict__ src, float4* __restrict__ dst,
    const int n4, const int z, const int stride4)
{
  int i = blockIdx.x * 256 + threadIdx.x;
  if (i >= n4) return;
  float s0 = 0.f, s1 = 0.f, s2 = 0.f, s3 = 0.f;
  const float4* p = src + i;
  #pragma unroll 8
  for (int zz = 0; zz < z; ++zz){
    float4 v = p[(size_t)zz * stride4];
    s0 += v.x; s1 += v.y; s2 += v.z; s3 += v.w;
  }
  float4 o; o.x = s0; o.y = s1; o.z = s2; o.w = s3;
  dst[i] = o;
}

// ---------------------------------------------------------------------------
// K1 (partials): XPz[b][k][c] = sum_{t in 128-chunk z} sb[b,t,k]*x[b,t,c]
//                XPz[xbar][b][c] = sum_t x[b,t,c]   (kg==0 lanes)
// grid (4 c-tiles, B, 32 z), block 256. Two 64-t stage/compute rounds over
// ONE LDS buffer; stage-1 bursts (16 x-f4 + 8 sb) issued BEFORE stage-0
// compute (manual 1-deep pipeline; r7 lesson). x read ONCE from HBM.
// LDS = 65536 + 9216 = 74752 B -> 2 blocks/CU (512-block grid fully resident).
// z-record = 135168 floats: [ xs_z (131072) ; xbar_z (4096) ].
// ---------------------------------------------------------------------------
__global__ __launch_bounds__(256) void k1_spectral_p(
    const float* __restrict__ x, const float* __restrict__ sb,
    float* __restrict__ XP)
{
  const int ct = blockIdx.x;
  const int b  = blockIdx.y;
  const int zz = blockIdx.z;
  const int t0 = zz * 128;
  const int cs = threadIdx.x & 63;
  const int kg = threadIdx.x >> 6;          // wave id = k-group
  __shared__ __align__(16) float4 xt[4096];   // 64t x 64 f4 (256 c) 64KB
  __shared__ __align__(16) float sbs[64][36]; // 9.2KB

  const float4* xg = (const float4*)(x + (size_t)(b * T_ + t0) * D_ + ct * 256);
  // ---- stage 0: burst loads -> LDS
  {
    float4 rv[16]; float rs[8];
    #pragma unroll
    for (int j = 0; j < 16; j++){
      int idx = threadIdx.x + j * 256; int t = idx >> 6, cq = idx & 63;
      rv[j] = xg[(size_t)t * 256 + cq];
    }
    #pragma unroll
    for (int i = 0; i < 8; i++){
      int idx = threadIdx.x + i * 256; int t = idx >> 5, kk = idx & 31;
      rs[i] = sb[(size_t)(b * T_ + t0 + t) * K_ + kk];
    }
    #pragma unroll
    for (int j = 0; j < 16; j++) xt[threadIdx.x + j * 256] = rv[j];
    #pragma unroll
    for (int i = 0; i < 8; i++){
      int idx = threadIdx.x + i * 256; sbs[idx >> 5][idx & 31] = rs[i];
    }
  }
  __syncthreads();
  // ---- prefetch stage 1 (rows t0+64..t0+127) while computing stage 0
  float4 rv1[16]; float rs1[8];
  #pragma unroll
  for (int j = 0; j < 16; j++){
    int idx = threadIdx.x + j * 256; int t = idx >> 6, cq = idx & 63;
    rv1[j] = xg[(size_t)(t + 64) * 256 + cq];
  }
  #pragma unroll
  for (int i = 0; i < 8; i++){
    int idx = threadIdx.x + i * 256; int t = idx >> 5, kk = idx & 31;
    rs1[i] = sb[(size_t)(b * T_ + t0 + 64 + t) * K_ + kk];
  }

  float4 acc[8];
  #pragma unroll
  for (int k = 0; k < 8; k++){ acc[k].x = 0.f; acc[k].y = 0.f;
                               acc[k].z = 0.f; acc[k].w = 0.f; }
  float4 am; am.x = 0.f; am.y = 0.f; am.z = 0.f; am.w = 0.f;
  // ---- compute stage 0
  #pragma unroll 4
  for (int t = 0; t < 64; ++t){
    float4 xv = xt[t * 64 + cs];
    if (kg == 0){ am.x += xv.x; am.y += xv.y; am.z += xv.z; am.w += xv.w; }
    const float4* srow = (const float4*)&sbs[t][kg * 8];  // wave-uniform
    float4 s0 = srow[0], s1 = srow[1];
    fma4(acc[0], s0.x, xv); fma4(acc[1], s0.y, xv);
    fma4(acc[2], s0.z, xv); fma4(acc[3], s0.w, xv);
    fma4(acc[4], s1.x, xv); fma4(acc[5], s1.y, xv);
    fma4(acc[6], s1.z, xv); fma4(acc[7], s1.w, xv);
  }
  __syncthreads();
  // ---- write stage 1 to LDS
  #pragma unroll
  for (int j = 0; j < 16; j++) xt[threadIdx.x + j * 256] = rv1[j];
  #pragma unroll
  for (int i = 0; i < 8; i++){
    int idx = threadIdx.x + i * 256; sbs[idx >> 5][idx & 31] = rs1[i];
  }
  __syncthreads();
  // ---- compute stage 1 (same accumulators)
  #pragma unroll 4
  for (int t = 0; t < 64; ++t){
    float4 xv = xt[t * 64 + cs];
    if (kg == 0){ am.x += xv.x; am.y += xv.y; am.z += xv.z; am.w += xv.w; }
    const float4* srow = (const float4*)&sbs[t][kg * 8];
    float4 s0 = srow[0], s1 = srow[1];
    fma4(acc[0], s0.x, xv); fma4(acc[1], s0.y, xv);
    fma4(acc[2], s0.z, xv); fma4(acc[3], s0.w, xv);
    fma4(acc[4], s1.x, xv); fma4(acc[5], s1.y, xv);
    fma4(acc[6], s1.z, xv); fma4(acc[7], s1.w, xv);
  }
  const int c = ct * 256 + cs * 4;
  float* o = XP + (size_t)zz * 135168 + (size_t)(b * K_ + kg * 8) * D_ + c;
  #pragma unroll
  for (int k = 0; k < 8; k++) *(float4*)(o + (size_t)k * D_) = acc[k];
  if (kg == 0)
    *(float4*)(XP + (size_t)zz * 135168 + 131072 + b * D_ + c) = am;
}

// ---------------------------------------------------------------------------
// gemm_qkv: qkv GEMM partials. Cp[z][m][n] = sum_{c in 128-chunk} A[m][c]*W[n][c]
// A = 192x1024 (xs;xbar;pad), W = Wqkv 3072x1024. grid (24, 3, 8), block 256.
// 64m x 128n block tile, 4m x 8n thread tile. TWO 64-c chunks with manual
// 1-deep prefetch (chunk-1 bursts before chunk-0 compute). LDS 51.2KB.
// W read as two half-tiles (tx*4, 64+tx*4): b128 reads 2-way aliased (free).
// ---------------------------------------------------------------------------
__global__ __launch_bounds__(256) void gemm_qkv(
    const float* __restrict__ A, const float* __restrict__ W,
    float* __restrict__ Cp)
{
  __shared__ __align__(16) float As[64][68];   // [c][m] 17.4 KB
  __shared__ __align__(16) float Ws[64][132];  // [c][n] 33.8 KB
  const int nt = blockIdx.x, mt = blockIdx.y;
  const int cb0 = blockIdx.z * 128;
  const int sc = threadIdx.x & 63, sr = threadIdx.x >> 6;
  const float* Ap = A + (size_t)(mt * 64 + sr) * 1024 + cb0 + sc;
  const float* Wp = W + (size_t)(nt * 128 + sr) * 1024 + cb0 + sc;
  // ---- chunk 0: burst loads -> LDS
  {
    float ra[16], rw[32];
    #pragma unroll
    for (int i = 0; i < 16; i++) ra[i] = Ap[(size_t)(i * 4) * 1024];
    #pragma unroll
    for (int i = 0; i < 32; i++) rw[i] = Wp[(size_t)(i * 4) * 1024];
    #pragma unroll
    for (int i = 0; i < 16; i++) As[sc][sr + i * 4] = ra[i];
    #pragma unroll
    for (int i = 0; i < 32; i++) Ws[sc][sr + i * 4] = rw[i];
  }
  __syncthreads();
  // ---- prefetch chunk 1 (c += 64)
  float ra1[16], rw1[32];
  #pragma unroll
  for (int i = 0; i < 16; i++) ra1[i] = Ap[(size_t)(i * 4) * 1024 + 64];
  #pragma unroll
  for (int i = 0; i < 32; i++) rw1[i] = Wp[(size_t)(i * 4) * 1024 + 64];

  const int tx = threadIdx.x & 15, ty = threadIdx.x >> 4;
  float4 acc[4][2];
  #pragma unroll
  for (int i = 0; i < 4; i++)
    #pragma unroll
    for (int j = 0; j < 2; j++){ acc[i][j].x = 0.f; acc[i][j].y = 0.f;
                                 acc[i][j].z = 0.f; acc[i][j].w = 0.f; }
  // ---- compute chunk 0
  #pragma unroll 8
  for (int c = 0; c < 64; ++c){
    const float4 a4 = *(const float4*)&As[c][ty * 4];
    const float4 w0 = *(const float4*)&Ws[c][tx * 4];
    const float4 w1 = *(const float4*)&Ws[c][64 + tx * 4];
    fma4(acc[0][0], a4.x, w0); fma4(acc[0][1], a4.x, w1);
    fma4(acc[1][0], a4.y, w0); fma4(acc[1][1], a4.y, w1);
    fma4(acc[2][0], a4.z, w0); fma4(acc[2][1], a4.z, w1);
    fma4(acc[3][0], a4.w, w0); fma4(acc[3][1], a4.w, w1);
  }
  __syncthreads();
  // ---- write chunk 1 to LDS
  #pragma unroll
  for (int i = 0; i < 16; i++) As[sc][sr + i * 4] = ra1[i];
  #pragma unroll
  for (int i = 0; i < 32; i++) Ws[sc][sr + i * 4] = rw1[i];
  __syncthreads();
  // ---- compute chunk 1
  #pragma unroll 8
  for (int c = 0; c < 64; ++c){
    const float4 a4 = *(const float4*)&As[c][ty * 4];
    const float4 w0 = *(const float4*)&Ws[c][tx * 4];
    const float4 w1 = *(const float4*)&Ws[c][64 + tx * 4];
    fma4(acc[0][0], a4.x, w0); fma4(acc[0][1], a4.x, w1);
    fma4(acc[1][0], a4.y, w0); fma4(acc[1][1], a4.y, w1);
    fma4(acc[2][0], a4.z, w0); fma4(acc[2][1], a4.z, w1);
    fma4(acc[3][0], a4.w, w0); fma4(acc[3][1], a4.w, w1);
  }
  float* cp = Cp + (size_t)blockIdx.z * 589824;
  #pragma unroll
  for (int i = 0; i < 4; i++){
    float* row = cp + (size_t)(mt * 64 + ty * 4 + i) * 3072 + nt * 128;
    *(float4*)(row + tx * 4)      = acc[i][0];
    *(float4*)(row + 64 + tx * 4) = acc[i][1];
  }
}

// ---------------------------------------------------------------------------
// gemm_aw_p (gemm#2): Cp[z][m][n] = sum_{c in split} A[m][c]*W[n][c]
// grid (16, 2, 16), block 256; 64x64 tile; c-chunk 32; reg dbuf.
// ---------------------------------------------------------------------------
__global__ __launch_bounds__(256) void gemm_aw_p(
    const float* __restrict__ A, const float* __restrict__ W,
    float* __restrict__ Cp, const int N, const int cPerSplit, const int MN)
{
  __shared__ __align__(16) float As[32][68];
  __shared__ __align__(16) float Ws[32][68];
  const int nt = blockIdx.x, mt = blockIdx.y;
  const int cbase = blockIdx.z * cPerSplit;
  const int tx = threadIdx.x & 15, ty = threadIdx.x >> 4;
  const int sc = threadIdx.x & 31, sr = threadIdx.x >> 5;
  float acc[4][4];
  #pragma unroll
  for (int i = 0; i < 4; i++)
    #pragma unroll
    for (int j = 0; j < 4; j++) acc[i][j] = 0.f;

  float ra[8], rw[8];
  const float* Ap = A + (size_t)(mt * 64 + sr) * 1024 + cbase + sc;
  const float* Wp = W + (size_t)(nt * 64 + sr) * 1024 + cbase + sc;
  #pragma unroll
  for (int i = 0; i < 8; i++){ ra[i] = Ap[(size_t)(i * 8) * 1024];
                               rw[i] = Wp[(size_t)(i * 8) * 1024]; }
  #pragma unroll
  for (int i = 0; i < 8; i++){ As[sc][sr + i * 8] = ra[i];
                               Ws[sc][sr + i * 8] = rw[i]; }
  __syncthreads();

  for (int cc = 32; cc < cPerSplit; cc += 32){
    #pragma unroll
    for (int i = 0; i < 8; i++){ ra[i] = Ap[(size_t)(i * 8) * 1024 + cc];
                                 rw[i] = Wp[(size_t)(i * 8) * 1024 + cc]; }
    #pragma unroll 4
    for (int c = 0; c < 32; ++c){
      const float4 a4 = *(const float4*)&As[c][ty * 4];
      const float4 w4 = *(const float4*)&Ws[c][tx * 4];
      acc[0][0] = fmaf(a4.x, w4.x, acc[0][0]);
      acc[0][1] = fmaf(a4.x, w4.y, acc[0][1]);
      acc[0][2] = fmaf(a4.x, w4.z, acc[0][2]);
      acc[0][3] = fmaf(a4.x, w4.w, acc[0][3]);
      acc[1][0] = fmaf(a4.y, w4.x, acc[1][0]);
      acc[1][1] = fmaf(a4.y, w4.y, acc[1][1]);
      acc[1][2] = fmaf(a4.y, w4.z, acc[1][2]);
      acc[1][3] = fmaf(a4.y, w4.w, acc[1][3]);
      acc[2][0] = fmaf(a4.z, w4.x, acc[2][0]);
      acc[2][1] = fmaf(a4.z, w4.y, acc[2][1]);
      acc[2][2] = fmaf(a4.z, w4.z, acc[2][2]);
      acc[2][3] = fmaf(a4.z, w4.w, acc[2][3]);
      acc[3][0] = fmaf(a4.w, w4.x, acc[3][0]);
      acc[3][1] = fmaf(a4.w, w4.y, acc[3][1]);
      acc[3][2] = fmaf(a4.w, w4.z, acc[3][2]);
      acc[3][3] = fmaf(a4.w, w4.w, acc[3][3]);
    }
    __syncthreads();
    #pragma unroll
    for (int i = 0; i < 8; i++){ As[sc][sr + i * 8] = ra[i];
                                 Ws[sc][sr + i * 8] = rw[i]; }
    __syncthreads();
  }
  #pragma unroll 4
  for (int c = 0; c < 32; ++c){
    const float4 a4 = *(const float4*)&As[c][ty * 4];
    const float4 w4 = *(const float4*)&Ws[c][tx * 4];
    acc[0][0] = fmaf(a4.x, w4.x, acc[0][0]);
    acc[0][1] = fmaf(a4.x, w4.y, acc[0][1]);
    acc[0][2] = fmaf(a4.x, w4.z, acc[0][2]);
    acc[0][3] = fmaf(a4.x, w4.w, acc[0][3]);
    acc[1][0] = fmaf(a4.y, w4.x, acc[1][0]);
    acc[1][1] = fmaf(a4.y, w4.y, acc[1][1]);
    acc[1][2] = fmaf(a4.y, w4.z, acc[1][2]);
    acc[1][3] = fmaf(a4.y, w4.w, acc[1][3]);
    acc[2][0] = fmaf(a4.z, w4.x, acc[2][0]);
    acc[2][1] = fmaf(a4.z, w4.y, acc[2][1]);
    acc[2][2] = fmaf(a4.z, w4.z, acc[2][2]);
    acc[2][3] = fmaf(a4.z, w4.w, acc[2][3]);
    acc[3][0] = fmaf(a4.w, w4.x, acc[3][0]);
    acc[3][1] = fmaf(a4.w, w4.y, acc[3][1]);
    acc[3][2] = fmaf(a4.w, w4.z, acc[3][2]);
    acc[3][3] = fmaf(a4.w, w4.w, acc[3][3]);
  }
  float* cp = Cp + (size_t)blockIdx.z * MN;
  #pragma unroll
  for (int i = 0; i < 4; i++){
    float4 o; o.x = acc[i][0]; o.y = acc[i][1]; o.z = acc[i][2]; o.w = acc[i][3];
    *(float4*)(cp + (size_t)(mt * 64 + ty * 4 + i) * N + nt * 64 + tx * 4) = o;
  }
}

// ---------------------------------------------------------------------------
// K3: pulse (qkv row 128+b = xbar@Wqkv.T), attn_spec, soliton ODE, u=resp*v_spec
// grid 64 blocks (b*16+h), 64 threads. All outputs f32.
// ---------------------------------------------------------------------------
__global__ __launch_bounds__(64) void k3_small(
    const float* __restrict__ qkvC,
    const float* __restrict__ W1, const float* __restrict__ b1,
    const float* __restrict__ W2, const float* __restrict__ b2,
    const float* __restrict__ filt,
    const float* __restrict__ a_in, const float* __restrict__ b_in,
    float* __restrict__ u, float* __restrict__ out_pulse,
    float* __restrict__ out_resp)
{
  const int b = blockIdx.x >> 4, h = blockIdx.x & 15;
  const int d = threadIdx.x;
  __shared__ float qm[64];
  __shared__ float h1s[32];
  __shared__ float rsp[32];
  qm[d] = qkvC[(size_t)(128 + b) * 3072 + h * 64 + d] * (1.0f / 4096.0f);
  __syncthreads();
  if (d < 32){
    float z = b1[d];
    for (int j = 0; j < 64; j++) z = fmaf(qm[j], W1[d * 64 + j], z);
    h1s[d] = z / (1.0f + __expf(-z));             // silu
  }
  __syncthreads();
  if (d == 0){
    float z2 = b2[0];
    for (int j = 0; j < 32; j++) z2 = fmaf(h1s[j], W2[j], z2);
    out_pulse[b * H_ + h] = 4.0f + log1pf(__expf(z2));  // PULSE_BASE+softplus
  }
  if (d < 32){
    const int k = d;
    const float* qrow = qkvC + (size_t)(b * K_ + k) * 3072 + h * 64;
    const float* krow = qrow + 1024;
    float s = 0.f;
    for (int j = 0; j < 64; j++) s = fmaf(qrow[j], krow[j], s);
    float fg = 1.0f / (1.0f + __expf(-filt[h * 32 + k]));
    s = s * 0.125f * fg;                          // /sqrt(64)*sigmoid(filter)
    float av = a_in[0], bv = b_in[0];
    float sc = fmaxf(fabsf(s), 1e-6f);
    float sn = s / sc;
    float I  = (fabsf(s) > 0.5f) ? sn : 0.1f * sn;
    float v = 0.f, w = 0.f;
    #pragma unroll
    for (int it = 0; it < 5; ++it){
      float dv = v - v * v * v * (1.0f / 3.0f) - w + I;
      float dw = (v + av - bv * w) * 10.0f;       // /TAU
      v = fminf(fmaxf(v + 0.2f * dv, -3.0f), 3.0f);
      w = fminf(fmaxf(w + 0.2f * dw, -3.0f), 3.0f);
    }
    float r = v * sc;
    rsp[k] = r;
    out_resp[(b * H_ + h) * K_ + k] = r;
  }
  __syncthreads();
  for (int k = 0; k < 32; k++){
    u[(size_t)(b * K_ + k) * D_ + h * 64 + d] =
        rsp[k] * qkvC[(size_t)(b * K_ + k) * 3072 + 2048 + h * 64 + d];
  }
}

// ---------------------------------------------------------------------------
// k4_main: all out0 rows EXCEPT [896,1024); 32-row chunks x 256-e tiles.
// grid (4, 508), block 256 (4 waves). Wave w owns t-rows [w*8, w*8+8);
// lane owns e-quad. M is STREAMED from L2 per-k; only acc[8] live.
// ---------------------------------------------------------------------------
__global__ __launch_bounds__(256) void k4_main(
    const float* __restrict__ sb, const float* __restrict__ Mf,
    float* __restrict__ out)
{
  const int ct = blockIdx.x;
  const int yy = blockIdx.y;
  const int r0 = (yy < 28 ? yy : yy + 4) * 32;   // skip M home rows [896,1024)
  const int b  = r0 >> 12;
  const int w  = threadIdx.x >> 6;               // wave id: t-rows [w*8,w*8+8)
  const int ls = threadIdx.x & 63;               // lane: e-quad
  __shared__ __align__(16) float sbsT[32][36];   // [k][t], rows 16B-aligned
  #pragma unroll
  for (int i = 0; i < 4; i++){
    int idx = threadIdx.x + i * 256;             // 1024 = 32t * 32k
    int t = idx >> 5, k = idx & 31;
    sbsT[k][t] = sb[(size_t)(r0 + t) * K_ + k];
  }
  __syncthreads();
  float4 acc[8];
  #pragma unroll
  for (int i = 0; i < 8; i++){ acc[i].x = 0.f; acc[i].y = 0.f;
                               acc[i].z = 0.f; acc[i].w = 0.f; }
  const float4* Mg = (const float4*)(Mf + (size_t)b * K_ * D_);
  const int eq = ct * 64 + ls;                   // e-quad within D (256 f4)
  #pragma unroll 8
  for (int k = 0; k < 32; ++k){
    float4 mv = Mg[(size_t)k * 256 + eq];        // L2-hot stream
    const float4* srow = (const float4*)&sbsT[k][w * 8];  // wave-uniform
    float4 s0 = srow[0], s1 = srow[1];
    fma4(acc[0], s0.x, mv); fma4(acc[1], s0.y, mv);
    fma4(acc[2], s0.z, mv); fma4(acc[3], s0.w, mv);
    fma4(acc[4], s1.x, mv); fma4(acc[5], s1.y, mv);
    fma4(acc[6], s1.z, mv); fma4(acc[7], s1.w, mv);
  }
  float* op = out + (size_t)(r0 + w * 8) * D_ + eq * 4;
  #pragma unroll
  for (int i = 0; i < 8; i++)
    *(float4*)(op + (size_t)i * D_) = acc[i];
}

// ---------------------------------------------------------------------------
// k4_tailp: out0 rows [896,1024) — M's home — COLUMN-PARTITIONED.
// grid (64), block 256. Block j owns columns [j*16, j*16+16); race-free.
// ---------------------------------------------------------------------------
__global__ __launch_bounds__(256) void k4_tailp(
    const float* __restrict__ sb, const float* __restrict__ Mf,
    float* __restrict__ out)
{
  __shared__ float sbs[128][33];               // 16.9 KB
  __shared__ __align__(16) float Ms[32][16];   // 2 KB: this block's M columns
  const int j = blockIdx.x;
  #pragma unroll
  for (int i = 0; i < 2; i++){
    int idx = threadIdx.x + i * 256;           // 512 = 32k * 16e
    int k = idx >> 4, e = idx & 15;
    Ms[k][e] = Mf[(size_t)k * D_ + j * 16 + e];
  }
  #pragma unroll
  for (int i = 0; i < 16; i++){
    int idx = threadIdx.x + i * 256;           // 4096 = 128t * 32k
    int k = idx & 31, t = idx >> 5;
    sbs[t][k] = sb[(size_t)(896 + t) * K_ + k];
  }
  __syncthreads();
  const int t  = threadIdx.x >> 1;
  const int c0 = (threadIdx.x & 1) * 8;
  float a0 = 0.f, a1 = 0.f, a2 = 0.f, a3 = 0.f;
  float a4 = 0.f, a5 = 0.f, a6 = 0.f, a7 = 0.f;
  #pragma unroll
  for (int k = 0; k < 32; k++){
    float s = sbs[t][k];
    const float4 m0 = *(const float4*)&Ms[k][c0];
    const float4 m1 = *(const float4*)&Ms[k][c0 + 4];
    a0 = fmaf(s, m0.x, a0); a1 = fmaf(s, m0.y, a1);
    a2 = fmaf(s, m0.z, a2); a3 = fmaf(s, m0.w, a3);
    a4 = fmaf(s, m1.x, a4); a5 = fmaf(s, m1.y, a5);
    a6 = fmaf(s, m1.z, a6); a7 = fmaf(s, m1.w, a7);
  }
  float* op = out + (size_t)(896 + t) * D_ + j * 16 + c0;
  float4 o0; o0.x = a0; o0.y = a1; o0.z = a2; o0.w = a3;
  float4 o1; o1.x = a4; o1.y = a5; o1.z = a6; o1.w = a7;
  *(float4*)(op)     = o0;
  *(float4*)(op + 4) = o1;
}

// ---------------------------------------------------------------------------
extern "C" void kernel_launch(void* const* d_in, const int* in_sizes, int n_in,
                              void* d_out, int out_size, void* d_ws, size_t ws_size,
                              hipStream_t stream)
{
  const float* x    = (const float*)d_in[0];
  const float* sb   = (const float*)d_in[1];
  const float* Wqkv = (const float*)d_in[2];
  const float* Wout = (const float*)d_in[3];
  const float* a_in = (const float*)d_in[4];
  const float* b_in = (const float*)d_in[5];
  const float* W1   = (const float*)d_in[6];
  const float* b1   = (const float*)d_in[7];
  const float* W2   = (const float*)d_in[8];
  const float* b2   = (const float*)d_in[9];
  const float* filt = (const float*)d_in[10];

  float* outF = (float*)d_out;
  float* qkv  = outF + 196608;
  float* u    = outF + 786432;
  float* Mm   = outF + 917504;        // f32 M, out0 rows [896,1024)
  float* S    = outF + 1048576;       // partial slabs (sequentially reused)
  float* pulse = outF + 16777216;     // (B,H)   f32
  float* resp  = outF + 16777280;     // (B,H,K) f32

  // spectral projection partials (4 c-tiles, b=4, z=32 double-stage chunks)
  k1_spectral_p<<<dim3(4, 4, 32), 256, 0, stream>>>(x, sb, S);
  // single-stage reduce 32-deep into xs+xbar, zero gemm#1's pad rows
  reduce_zp<<<dim3(192), 256, 0, stream>>>((const float4*)S, (float4*)outF,
                                           33792, 32, 33792, 49152);

  // qkv GEMM: 8-way split-K partials (64x128 tile, 2x64c chunks) -> reduce
  gemm_qkv<<<dim3(24, 3, 8), 256, 0, stream>>>(outF, Wqkv, S);
  reduce_z<<<dim3(576), 256, 0, stream>>>((const float4*)S, (float4*)qkv,
                                          147456, 8, 147456);

  k3_small<<<dim3(64), dim3(64), 0, stream>>>(qkv, W1, b1, W2, b2,
                                              filt, a_in, b_in, u,
                                              pulse, resp);

  // out GEMM: 16-way split-K partials -> single 16-deep reduce into Mm
  gemm_aw_p<<<dim3(16, 2, 16), 256, 0, stream>>>(u, Wout, S, 1024, 64, 131072);
  reduce_z<<<dim3(128), 256, 0, stream>>>((const float4*)S, (float4*)Mm,
                                          32768, 16, 32768);

  // All rows except M's home: 32-row chunks x 4 e-tiles, M streamed from L2
  k4_main<<<dim3(4, 508), 256, 0, stream>>>(sb, Mm, outF);
  // M's home rows, column-partitioned across 64 blocks
  k4_tailp<<<dim3(64), 256, 0, stream>>>(sb, Mm, outF);
}